// Round 2
// baseline (235.367 us; speedup 1.0000x reference)
//
#include <hip/hip_runtime.h>

// Input: x (32, 256, 64, 64) fp32. STRIDE=2, P=2. H,W even -> no padding.
// Pass 1: per-batch sum of squares for each of 4 polyphase comps (argmax of
// L2-norm == argmax of sum-of-squares). Pass 2: gather winning component.

#define B 32
#define C 256
#define H 64
#define W 64
#define H2 32
#define W2 32
// float4s per batch in input: C*H*W/4
#define IN_F4_PER_BATCH (C * H * W / 4)      // 262144
// float4s per batch in output: C*H2*W2/4
#define OUT_F4_PER_BATCH (C * H2 * W2 / 4)   // 65536

__global__ void aps_zero(float* __restrict__ sums) {
    sums[threadIdx.x] = 0.0f;   // 128 = B*4 floats
}

__global__ __launch_bounds__(256) void aps_sums(const float4* __restrict__ x,
                                                float* __restrict__ sums) {
    const int b = blockIdx.y;
    const float4* xb = x + (size_t)b * IN_F4_PER_BATCH;
    float s0 = 0.f, s1 = 0.f, s2 = 0.f, s3 = 0.f;
    // f = ((c*H)+h)*16 + w4  -> (f>>4)&1 == h&1 (H even)
    for (int f = blockIdx.x * blockDim.x + threadIdx.x; f < IN_F4_PER_BATCH;
         f += gridDim.x * blockDim.x) {
        float4 v = xb[f];
        float e = v.x * v.x + v.z * v.z;   // w-parity 0
        float o = v.y * v.y + v.w * v.w;   // w-parity 1
        if ((f >> 4) & 1) { s2 += e; s3 += o; }
        else              { s0 += e; s1 += o; }
    }
    // wave (64-lane) shuffle reduction
    for (int off = 32; off; off >>= 1) {
        s0 += __shfl_down(s0, off);
        s1 += __shfl_down(s1, off);
        s2 += __shfl_down(s2, off);
        s3 += __shfl_down(s3, off);
    }
    __shared__ float sm[4][4];   // [wave][comp]
    const int lane = threadIdx.x & 63;
    const int wave = threadIdx.x >> 6;
    if (lane == 0) {
        sm[wave][0] = s0; sm[wave][1] = s1; sm[wave][2] = s2; sm[wave][3] = s3;
    }
    __syncthreads();
    if (threadIdx.x == 0) {
        float t0 = 0.f, t1 = 0.f, t2 = 0.f, t3 = 0.f;
        for (int w = 0; w < 4; ++w) {
            t0 += sm[w][0]; t1 += sm[w][1]; t2 += sm[w][2]; t3 += sm[w][3];
        }
        atomicAdd(&sums[b * 4 + 0], t0);
        atomicAdd(&sums[b * 4 + 1], t1);
        atomicAdd(&sums[b * 4 + 2], t2);
        atomicAdd(&sums[b * 4 + 3], t3);
    }
}

__global__ __launch_bounds__(256) void aps_gather(const float* __restrict__ x,
                                                  const float* __restrict__ sums,
                                                  float4* __restrict__ out) {
    const int b = blockIdx.y;
    const float* sb = sums + b * 4;
    // first-max argmax (strict > keeps lowest index on ties, matching jnp.argmax)
    float best = sb[0];
    int k = 0;
    if (sb[1] > best) { best = sb[1]; k = 1; }
    if (sb[2] > best) { best = sb[2]; k = 2; }
    if (sb[3] > best) { k = 3; }
    const int di = k >> 1;       // h offset
    const int dj = k & 1;        // w offset

    const int idx = blockIdx.x * blockDim.x + threadIdx.x;  // out float4 idx in batch
    const int t4 = idx & 7;             // which float4 of the 32-float out row
    const int i  = (idx >> 3) & 31;     // out row
    const int c  = idx >> 8;            // channel
    const float* row = x + (((size_t)(b * C + c) * H) + (2 * i + di)) * W;
    const float4* r4 = (const float4*)row + 2 * t4;
    float4 a  = r4[0];
    float4 bb = r4[1];
    float4 o;
    if (dj == 0) { o.x = a.x; o.y = a.z; o.z = bb.x; o.w = bb.z; }
    else         { o.x = a.y; o.y = a.w; o.z = bb.y; o.w = bb.w; }
    out[(size_t)b * OUT_F4_PER_BATCH + idx] = o;
}

extern "C" void kernel_launch(void* const* d_in, const int* in_sizes, int n_in,
                              void* d_out, int out_size, void* d_ws, size_t ws_size,
                              hipStream_t stream) {
    const float* x = (const float*)d_in[0];
    float* out = (float*)d_out;
    float* sums = (float*)d_ws;   // B*4 = 128 floats

    aps_zero<<<1, B * 4, 0, stream>>>(sums);
    aps_sums<<<dim3(64, B), 256, 0, stream>>>((const float4*)x, sums);
    aps_gather<<<dim3(OUT_F4_PER_BATCH / 256, B), 256, 0, stream>>>(x, sums,
                                                                    (float4*)out);
}

// Round 4
// 223.363 us; speedup vs baseline: 1.0537x; 1.0537x over previous
//
#include <hip/hip_runtime.h>

// Input: x (32, 256, 64, 64) fp32. STRIDE=2, P=2. H,W even -> no padding.
// Pass 1: per-(batch, block) partial sums of squares for the 4 polyphase
// components -> ws (no atomics, no zeroing). Pass 2: each gather block
// redundantly reduces its batch's 256 partials (L2-hit), takes argmax
// (strict > == jnp.argmax first-max tie rule), gathers winning component.

#define B 32
#define C 256
#define H 64
#define W 64
#define H2 32
#define W2 32
#define NBLK 64                              // pass-1 blocks per batch
#define IN_F4_PER_BATCH (C * H * W / 4)      // 262144
#define OUT_F4_PER_BATCH (C * H2 * W2 / 4)   // 65536

typedef float floatx4 __attribute__((ext_vector_type(4)));  // native vec for NT store

__global__ __launch_bounds__(256) void aps_partials(const float4* __restrict__ x,
                                                    float* __restrict__ ws) {
    const int b = blockIdx.y;
    const float4* xb = x + (size_t)b * IN_F4_PER_BATCH;
    float s0 = 0.f, s1 = 0.f, s2 = 0.f, s3 = 0.f;
    // f = ((c*H)+h)*16 + w4  -> (f>>4)&1 == h&1 (H even)
    for (int f = blockIdx.x * blockDim.x + threadIdx.x; f < IN_F4_PER_BATCH;
         f += gridDim.x * blockDim.x) {
        float4 v = xb[f];
        float e = v.x * v.x + v.z * v.z;   // w-parity 0
        float o = v.y * v.y + v.w * v.w;   // w-parity 1
        if ((f >> 4) & 1) { s2 += e; s3 += o; }
        else              { s0 += e; s1 += o; }
    }
    for (int off = 32; off; off >>= 1) {
        s0 += __shfl_down(s0, off);
        s1 += __shfl_down(s1, off);
        s2 += __shfl_down(s2, off);
        s3 += __shfl_down(s3, off);
    }
    __shared__ float sm[4][4];   // [wave][comp]
    const int lane = threadIdx.x & 63;
    const int wave = threadIdx.x >> 6;
    if (lane == 0) {
        sm[wave][0] = s0; sm[wave][1] = s1; sm[wave][2] = s2; sm[wave][3] = s3;
    }
    __syncthreads();
    if (threadIdx.x < 4) {   // thread k writes comp k's partial
        const int k = threadIdx.x;
        float t = sm[0][k] + sm[1][k] + sm[2][k] + sm[3][k];
        // layout: ws[(b*4 + comp)*NBLK + bx]  -> contiguous per (b,comp)
        ws[(b * 4 + k) * NBLK + blockIdx.x] = t;
    }
}

__global__ __launch_bounds__(256) void aps_gather(const float* __restrict__ x,
                                                  const float* __restrict__ ws,
                                                  float* __restrict__ out) {
    const int b = blockIdx.y;
    const int lane = threadIdx.x & 63;
    const int wave = threadIdx.x >> 6;   // 0..3 == component
    // redundant per-block reduction of this batch's 256 partials (L2-hot)
    float p = ws[(b * 4 + wave) * NBLK + lane];
    for (int off = 32; off; off >>= 1) p += __shfl_down(p, off);
    __shared__ float s4[4];
    if (lane == 0) s4[wave] = p;
    __syncthreads();
    float v0 = s4[0], v1 = s4[1], v2 = s4[2], v3 = s4[3];
    float best = v0;
    int k = 0;
    if (v1 > best) { best = v1; k = 1; }
    if (v2 > best) { best = v2; k = 2; }
    if (v3 > best) { k = 3; }
    const int di = k >> 1;       // h offset
    const int dj = k & 1;        // w offset

    const int idx = blockIdx.x * blockDim.x + threadIdx.x;  // out float4 idx in batch
    const int t4 = idx & 7;             // which float4 of the 32-float out row
    const int i  = (idx >> 3) & 31;     // out row
    const int c  = idx >> 8;            // channel
    const float* row = x + (((size_t)(b * C + c) * H) + (2 * i + di)) * W;
    const float4* r4 = (const float4*)row + 2 * t4;
    float4 a  = r4[0];
    float4 bb = r4[1];
    floatx4 o;
    if (dj == 0) { o.x = a.x; o.y = a.z; o.z = bb.x; o.w = bb.z; }
    else         { o.x = a.y; o.y = a.w; o.z = bb.y; o.w = bb.w; }
    // write-once output: nontemporal store keeps input resident in L2/L3
    floatx4* op = (floatx4*)(out + ((size_t)b * OUT_F4_PER_BATCH + idx) * 4);
    __builtin_nontemporal_store(o, op);
}

extern "C" void kernel_launch(void* const* d_in, const int* in_sizes, int n_in,
                              void* d_out, int out_size, void* d_ws, size_t ws_size,
                              hipStream_t stream) {
    const float* x = (const float*)d_in[0];
    float* out = (float*)d_out;
    float* ws = (float*)d_ws;   // B*4*NBLK = 8192 floats of partials

    aps_partials<<<dim3(NBLK, B), 256, 0, stream>>>((const float4*)x, ws);
    aps_gather<<<dim3(OUT_F4_PER_BATCH / 256, B), 256, 0, stream>>>(x, ws, out);
}

// Round 5
// 214.677 us; speedup vs baseline: 1.0964x; 1.0405x over previous
//
#include <hip/hip_runtime.h>

// Input: x (32, 256, 64, 64) fp32. STRIDE=2, P=2. H,W even -> no padding.
// Pass 1: per-(batch, block) partial sums of squares for the 4 polyphase
// components -> ws (no atomics, no zeroing). Branch-free: each iteration
// loads one even-h float4 and its paired odd-h float4 (+16 float4s = +1 row).
// Pass 2: each gather block redundantly reduces its batch's 64 partials
// (L2-hit), takes argmax (strict > == jnp.argmax first-max tie rule),
// gathers the winning component with NT stores.

#define B 32
#define C 256
#define H 64
#define W 64
#define H2 32
#define W2 32
#define NBLK 64                              // pass-1 blocks per batch
#define IN_F4_PER_BATCH (C * H * W / 4)      // 262144
#define PAIRS_PER_BATCH (IN_F4_PER_BATCH / 2)// 131072 even/odd row pairs
#define OUT_F4_PER_BATCH (C * H2 * W2 / 4)   // 65536

typedef float floatx4 __attribute__((ext_vector_type(4)));  // native vec for NT store

__global__ __launch_bounds__(256) void aps_partials(const float4* __restrict__ x,
                                                    float* __restrict__ ws) {
    const int b = blockIdx.y;
    const float4* xb = x + (size_t)b * IN_F4_PER_BATCH;
    float s0 = 0.f, s1 = 0.f, s2 = 0.f, s3 = 0.f;
    // g indexes even-h float4s: addr = (g>>4)*32 + (g&15); odd-h partner +16.
    for (int g = blockIdx.x * blockDim.x + threadIdx.x; g < PAIRS_PER_BATCH;
         g += gridDim.x * blockDim.x) {
        const int base = ((g >> 4) << 5) + (g & 15);
        float4 ve = xb[base];        // h even
        float4 vo = xb[base + 16];   // h odd (next row)
        s0 += ve.x * ve.x + ve.z * ve.z;   // (h0, w0)
        s1 += ve.y * ve.y + ve.w * ve.w;   // (h0, w1)
        s2 += vo.x * vo.x + vo.z * vo.z;   // (h1, w0)
        s3 += vo.y * vo.y + vo.w * vo.w;   // (h1, w1)
    }
    for (int off = 32; off; off >>= 1) {
        s0 += __shfl_down(s0, off);
        s1 += __shfl_down(s1, off);
        s2 += __shfl_down(s2, off);
        s3 += __shfl_down(s3, off);
    }
    __shared__ float sm[4][4];   // [wave][comp]
    const int lane = threadIdx.x & 63;
    const int wave = threadIdx.x >> 6;
    if (lane == 0) {
        sm[wave][0] = s0; sm[wave][1] = s1; sm[wave][2] = s2; sm[wave][3] = s3;
    }
    __syncthreads();
    if (threadIdx.x < 4) {   // thread k writes comp k's partial
        const int k = threadIdx.x;
        float t = sm[0][k] + sm[1][k] + sm[2][k] + sm[3][k];
        // layout: ws[(b*4 + comp)*NBLK + bx]  -> contiguous per (b,comp)
        ws[(b * 4 + k) * NBLK + blockIdx.x] = t;
    }
}

__global__ __launch_bounds__(256) void aps_gather(const float* __restrict__ x,
                                                  const float* __restrict__ ws,
                                                  float* __restrict__ out) {
    const int b = blockIdx.y;
    const int lane = threadIdx.x & 63;
    const int wave = threadIdx.x >> 6;   // 0..3 == component
    // redundant per-block reduction of this batch's 64 partials (L2-hot)
    float p = ws[(b * 4 + wave) * NBLK + lane];
    for (int off = 32; off; off >>= 1) p += __shfl_down(p, off);
    __shared__ float s4[4];
    if (lane == 0) s4[wave] = p;
    __syncthreads();
    float v0 = s4[0], v1 = s4[1], v2 = s4[2], v3 = s4[3];
    float best = v0;
    int k = 0;
    if (v1 > best) { best = v1; k = 1; }
    if (v2 > best) { best = v2; k = 2; }
    if (v3 > best) { k = 3; }
    const int di = k >> 1;       // h offset
    const int dj = k & 1;        // w offset

    const int idx = blockIdx.x * blockDim.x + threadIdx.x;  // out float4 idx in batch
    const int t4 = idx & 7;             // which float4 of the 32-float out row
    const int i  = (idx >> 3) & 31;     // out row
    const int c  = idx >> 8;            // channel
    const float* row = x + (((size_t)(b * C + c) * H) + (2 * i + di)) * W;
    const float4* r4 = (const float4*)row + 2 * t4;
    float4 a  = r4[0];
    float4 bb = r4[1];
    floatx4 o;
    if (dj == 0) { o.x = a.x; o.y = a.z; o.z = bb.x; o.w = bb.z; }
    else         { o.x = a.y; o.y = a.w; o.z = bb.y; o.w = bb.w; }
    // write-once output: nontemporal store keeps input resident in L2/L3
    floatx4* op = (floatx4*)(out + ((size_t)b * OUT_F4_PER_BATCH + idx) * 4);
    __builtin_nontemporal_store(o, op);
}

extern "C" void kernel_launch(void* const* d_in, const int* in_sizes, int n_in,
                              void* d_out, int out_size, void* d_ws, size_t ws_size,
                              hipStream_t stream) {
    const float* x = (const float*)d_in[0];
    float* out = (float*)d_out;
    float* ws = (float*)d_ws;   // B*4*NBLK = 8192 floats of partials

    aps_partials<<<dim3(NBLK, B), 256, 0, stream>>>((const float4*)x, ws);
    aps_gather<<<dim3(OUT_F4_PER_BATCH / 256, B), 256, 0, stream>>>(x, ws, out);
}